// Round 2
// baseline (515.411 us; speedup 1.0000x reference)
//
#include <hip/hip_runtime.h>
#include <hip/hip_cooperative_groups.h>
#include <hip/hip_fp16.h>

#define NB 4
#define NP 32768
#define NK 16
#define ND 8
#define EPSV 1e-6f

namespace cg = cooperative_groups;

// d_ws layout: [0..256) : 4 banks x 16 float accumulators (sum[8], sumsq[8] per bank).
// Banked to cut same-cacheline atomic contention 4x (grid.sync waits on the drain).

// ============================= fused cooperative kernel ================================
// one thread per (b, n, kq), kq = k/4  ->  4*32768*4 = 524288 threads = 2048 blocks.
// 2048 blocks == 256 CUs * 8 blocks/CU; __launch_bounds__(256,8) caps VGPR<=64 so all
// blocks are co-resident (required for grid.sync correctness & coop-launch validation).
__global__ __launch_bounds__(256, 8) void lse_fused(
    const float* __restrict__ coords,
    const float* __restrict__ features,
    const int*   __restrict__ knn_idx,
    const float* __restrict__ knn_dist,
    const int*   __restrict__ mask,
    const float* __restrict__ conv_w,
    const float* __restrict__ conv_b,
    const float* __restrict__ bn_gamma,
    const float* __restrict__ bn_beta,
    float*       __restrict__ accum,
    float*       __restrict__ out)
{
    const int gid = blockIdx.x * 256 + threadIdx.x;
    const int b   = gid >> 17;                 // NP*4 = 2^17 threads per batch
    const int r   = gid & (NP * 4 - 1);
    const int n   = r >> 2;
    const int k0  = (r & 3) * 4;

    const float* cbase = coords + (size_t)b * NP * 3;
    const float  cx = cbase[n * 3 + 0];
    const float  cy = cbase[n * 3 + 1];
    const float  cz = cbase[n * 3 + 2];

    const size_t p  = ((size_t)(b * NP + n)) * NK + k0;
    const int4   id = *(const int4*)(knn_idx + p);     // 16B coalesced
    float4       dv = *(const float4*)(knn_dist + p);  // 16B coalesced
    if (mask[b * NP + n] == 0) {
        dv.x = dv.y = dv.z = dv.w = __builtin_inff();
    }
    const int   js[4] = {id.x < 0 ? 0 : id.x, id.y < 0 ? 0 : id.y,
                         id.z < 0 ? 0 : id.z, id.w < 0 ? 0 : id.w};
    const float ds4[4] = {dv.x, dv.y, dv.z, dv.w};

    float nbx[4], nby[4], nbz[4];
#pragma unroll
    for (int t = 0; t < 4; ++t) {
        const float* nb = cbase + (size_t)js[t] * 3;   // L1/L2-resident gather
        nbx[t] = nb[0]; nby[t] = nb[1]; nbz[t] = nb[2];
    }

    // ---- Phase A: conv once, x kept packed fp16 in registers (16 VGPRs) ----
    float sum[ND], sq[ND];
#pragma unroll
    for (int d = 0; d < ND; ++d) { sum[d] = 0.f; sq[d] = 0.f; }

    uint32_t xp[4][4];   // [t][dpair] : half2(x[2dp], x[2dp+1])
#pragma unroll
    for (int dp = 0; dp < 4; ++dp) {
        const int d0 = 2 * dp, d1 = d0 + 1;
        const float* wA = conv_w + d0 * 10;            // uniform -> scalar loads
        const float* wB = conv_w + d1 * 10;
        const float aA0 = wA[0] + wA[6], aA1 = wA[1] + wA[7], aA2 = wA[2] + wA[8];
        const float eA0 = wA[3] - wA[6], eA1 = wA[4] - wA[7], eA2 = wA[5] - wA[8];
        const float wA9 = wA[9],         cbA = conv_b[d0];
        const float aB0 = wB[0] + wB[6], aB1 = wB[1] + wB[7], aB2 = wB[2] + wB[8];
        const float eB0 = wB[3] - wB[6], eB1 = wB[4] - wB[7], eB2 = wB[5] - wB[8];
        const float wB9 = wB[9],         cbB = conv_b[d1];
#pragma unroll
        for (int t = 0; t < 4; ++t) {
            float xA = fmaf(aA0, cx, fmaf(aA1, cy, fmaf(aA2, cz,
                       fmaf(eA0, nbx[t], fmaf(eA1, nby[t], fmaf(eA2, nbz[t],
                       fmaf(wA9, ds4[t], cbA)))))));
            float xB = fmaf(aB0, cx, fmaf(aB1, cy, fmaf(aB2, cz,
                       fmaf(eB0, nbx[t], fmaf(eB1, nby[t], fmaf(eB2, nbz[t],
                       fmaf(wB9, ds4[t], cbB)))))));
            sum[d0] += xA; sq[d0] = fmaf(xA, xA, sq[d0]);
            sum[d1] += xB; sq[d1] = fmaf(xB, xB, sq[d1]);
            __half2 h = __floats2half2_rn(xA, xB);
            xp[t][dp] = *(const uint32_t*)&h;
        }
    }

    // BN-independent feature broadcast planes (channels ND..2ND-1) — overlaps latency
    const float* fb = features + (size_t)b * ND * NP;
#pragma unroll
    for (int d = 0; d < ND; ++d) {
        const float v = fb[d * NP + n];
        *(float4*)(out + ((((size_t)(b * 2 * ND + ND + d)) * NP + n) << 4) + k0) =
            make_float4(v, v, v, v);
    }

    // ---- stats reduction: wave shuffle -> LDS -> 16 atomics into bank (blk&3) ----
#pragma unroll
    for (int d = 0; d < ND; ++d) {
        float s = sum[d], s2 = sq[d];
#pragma unroll
        for (int off = 32; off > 0; off >>= 1) {
            s  += __shfl_down(s,  off);
            s2 += __shfl_down(s2, off);
        }
        sum[d] = s; sq[d] = s2;
    }
    __shared__ float lred[4][16];
    const int wave = threadIdx.x >> 6, lane = threadIdx.x & 63;
    if (lane == 0) {
#pragma unroll
        for (int d = 0; d < ND; ++d) {
            lred[wave][d]     = sum[d];
            lred[wave][8 + d] = sq[d];
        }
    }
    __syncthreads();
    if (threadIdx.x < 16) {
        float v = lred[0][threadIdx.x] + lred[1][threadIdx.x]
                + lred[2][threadIdx.x] + lred[3][threadIdx.x];
        atomicAdd(&accum[(blockIdx.x & 3) * 16 + threadIdx.x], v);
    }

    // ---- grid-wide barrier: stats complete everywhere ----
    cg::this_grid().sync();

    // ---- Phase B: lane-parallel accum load + shfl combine, BN fold, relu, store ----
    // lane l reads accum[l] (64 floats = 4 banks x 16); combine via shuffles.
    float av = __hip_atomic_load(&accum[lane], __ATOMIC_RELAXED,
                                 __HIP_MEMORY_SCOPE_AGENT);
    float fs[ND], fq[ND];
#pragma unroll
    for (int i = 0; i < ND; ++i) {
        fs[i] = __shfl(av, i)     + __shfl(av, 16 + i)
              + __shfl(av, 32 + i) + __shfl(av, 48 + i);
        fq[i] = __shfl(av, 8 + i)  + __shfl(av, 24 + i)
              + __shfl(av, 40 + i) + __shfl(av, 56 + i);
    }

    const float invM = 1.0f / (float)(NB * NP * NK);
#pragma unroll
    for (int dp = 0; dp < 4; ++dp) {
        const int d0 = 2 * dp, d1 = d0 + 1;
        const float m0 = fs[d0] * invM;
        const float v0 = fmaf(-m0, m0, fq[d0] * invM);
        const float g0 = bn_gamma[d0] * rsqrtf(v0 + EPSV);
        const float s0 = fmaf(-m0, g0, bn_beta[d0]);
        const float m1 = fs[d1] * invM;
        const float v1 = fmaf(-m1, m1, fq[d1] * invM);
        const float g1 = bn_gamma[d1] * rsqrtf(v1 + EPSV);
        const float s1 = fmaf(-m1, g1, bn_beta[d1]);

        float4 y0, y1;
#pragma unroll
        for (int t = 0; t < 4; ++t) {
            __half2 h; *(uint32_t*)&h = xp[t][dp];
            float2 f = __half22float2(h);
            (&y0.x)[t] = fmaxf(fmaf(f.x, g0, s0), 0.f);
            (&y1.x)[t] = fmaxf(fmaf(f.y, g1, s1), 0.f);
        }
        *(float4*)(out + ((((size_t)(b * 2 * ND + d0)) * NP + n) << 4) + k0) = y0;
        *(float4*)(out + ((((size_t)(b * 2 * ND + d1)) * NP + n) << 4) + k0) = y1;
    }
}

// ============================= fallback (non-cooperative) ==============================
__global__ __launch_bounds__(256) void lse_stats(
    const float* __restrict__ coords,
    const int*   __restrict__ knn_idx,
    const float* __restrict__ knn_dist,
    const int*   __restrict__ mask,
    const float* __restrict__ conv_w,
    const float* __restrict__ conv_b,
    float*       __restrict__ accum)
{
    const int gid = blockIdx.x * 256 + threadIdx.x;
    const int b   = gid >> 17;
    const int r   = gid & (NP * 4 - 1);
    const int n   = r >> 2;
    const int k0  = (r & 3) * 4;

    float a0[ND], a1[ND], a2[ND], e0[ND], e1[ND], e2[ND], w9[ND], cb[ND];
#pragma unroll
    for (int d = 0; d < ND; ++d) {
        const float* w = conv_w + d * 10;
        a0[d] = w[0] + w[6]; a1[d] = w[1] + w[7]; a2[d] = w[2] + w[8];
        e0[d] = w[3] - w[6]; e1[d] = w[4] - w[7]; e2[d] = w[5] - w[8];
        w9[d] = w[9];        cb[d] = conv_b[d];
    }

    const float* cbase = coords + (size_t)b * NP * 3;
    const float cx = cbase[n*3], cy = cbase[n*3+1], cz = cbase[n*3+2];
    const size_t p  = ((size_t)(b * NP + n)) * NK + k0;
    const int4   id = *(const int4*)(knn_idx + p);
    float4       dv = *(const float4*)(knn_dist + p);
    if (mask[b * NP + n] == 0) dv.x = dv.y = dv.z = dv.w = __builtin_inff();
    const int   js[4] = {id.x < 0 ? 0 : id.x, id.y < 0 ? 0 : id.y,
                         id.z < 0 ? 0 : id.z, id.w < 0 ? 0 : id.w};
    const float ds4[4] = {dv.x, dv.y, dv.z, dv.w};

    float sum[ND], sq[ND];
#pragma unroll
    for (int d = 0; d < ND; ++d) { sum[d] = 0.f; sq[d] = 0.f; }
#pragma unroll
    for (int t = 0; t < 4; ++t) {
        const float* nb = cbase + (size_t)js[t] * 3;
        const float nx = nb[0], ny = nb[1], nz = nb[2];
#pragma unroll
        for (int d = 0; d < ND; ++d) {
            float x = fmaf(a0[d], cx, fmaf(a1[d], cy, fmaf(a2[d], cz,
                      fmaf(e0[d], nx, fmaf(e1[d], ny, fmaf(e2[d], nz,
                      fmaf(w9[d], ds4[t], cb[d])))))));
            sum[d] += x; sq[d] = fmaf(x, x, sq[d]);
        }
    }
#pragma unroll
    for (int d = 0; d < ND; ++d) {
        float s = sum[d], s2 = sq[d];
#pragma unroll
        for (int off = 32; off > 0; off >>= 1) {
            s += __shfl_down(s, off); s2 += __shfl_down(s2, off);
        }
        sum[d] = s; sq[d] = s2;
    }
    __shared__ float lred[4][16];
    const int wave = threadIdx.x >> 6, lane = threadIdx.x & 63;
    if (lane == 0) {
#pragma unroll
        for (int d = 0; d < ND; ++d) { lred[wave][d] = sum[d]; lred[wave][8+d] = sq[d]; }
    }
    __syncthreads();
    if (threadIdx.x < 16) {
        float v = lred[0][threadIdx.x] + lred[1][threadIdx.x]
                + lred[2][threadIdx.x] + lred[3][threadIdx.x];
        atomicAdd(&accum[(blockIdx.x & 3) * 16 + threadIdx.x], v);
    }
}

__global__ __launch_bounds__(256) void lse_write(
    const float* __restrict__ coords,
    const float* __restrict__ features,
    const int*   __restrict__ knn_idx,
    const float* __restrict__ knn_dist,
    const int*   __restrict__ mask,
    const float* __restrict__ conv_w,
    const float* __restrict__ conv_b,
    const float* __restrict__ accum,
    const float* __restrict__ bn_gamma,
    const float* __restrict__ bn_beta,
    float*       __restrict__ out)
{
    const int gid = blockIdx.x * 256 + threadIdx.x;
    const int b   = gid >> 17;
    const int r   = gid & (NP * 4 - 1);
    const int n   = r >> 2;
    const int k0  = (r & 3) * 4;
    const int lane = threadIdx.x & 63;

    float av = accum[lane];
    float fs[ND], fq[ND];
#pragma unroll
    for (int i = 0; i < ND; ++i) {
        fs[i] = __shfl(av, i) + __shfl(av, 16+i) + __shfl(av, 32+i) + __shfl(av, 48+i);
        fq[i] = __shfl(av, 8+i) + __shfl(av, 24+i) + __shfl(av, 40+i) + __shfl(av, 56+i);
    }
    const float invM = 1.0f / (float)(NB * NP * NK);
    float a0[ND], a1[ND], a2[ND], e0[ND], e1[ND], e2[ND], w9[ND], cb[ND];
#pragma unroll
    for (int d = 0; d < ND; ++d) {
        const float* w = conv_w + d * 10;
        const float mean = fs[d] * invM;
        const float var  = fmaf(-mean, mean, fq[d] * invM);
        const float g    = bn_gamma[d] * rsqrtf(var + EPSV);
        const float sh   = fmaf(-mean, g, bn_beta[d]);
        a0[d] = (w[0]+w[6])*g; a1[d] = (w[1]+w[7])*g; a2[d] = (w[2]+w[8])*g;
        e0[d] = (w[3]-w[6])*g; e1[d] = (w[4]-w[7])*g; e2[d] = (w[5]-w[8])*g;
        w9[d] = w[9]*g;        cb[d] = fmaf(conv_b[d], g, sh);
    }

    const float* cbase = coords + (size_t)b * NP * 3;
    const float cx = cbase[n*3], cy = cbase[n*3+1], cz = cbase[n*3+2];
    const size_t p  = ((size_t)(b * NP + n)) * NK + k0;
    const int4   id = *(const int4*)(knn_idx + p);
    float4       dv = *(const float4*)(knn_dist + p);
    if (mask[b * NP + n] == 0) dv.x = dv.y = dv.z = dv.w = __builtin_inff();
    const int   js[4] = {id.x < 0 ? 0 : id.x, id.y < 0 ? 0 : id.y,
                         id.z < 0 ? 0 : id.z, id.w < 0 ? 0 : id.w};
    const float ds4[4] = {dv.x, dv.y, dv.z, dv.w};

#pragma unroll
    for (int t = 0; t < 4; ++t) {
        const float* nb = cbase + (size_t)js[t] * 3;
        const float nx = nb[0], ny = nb[1], nz = nb[2];
        float xv[ND];
#pragma unroll
        for (int d = 0; d < ND; ++d) {
            xv[d] = fmaxf(fmaf(a0[d], cx, fmaf(a1[d], cy, fmaf(a2[d], cz,
                    fmaf(e0[d], nx, fmaf(e1[d], ny, fmaf(e2[d], nz,
                    fmaf(w9[d], ds4[t], cb[d]))))))), 0.f);
        }
#pragma unroll
        for (int d = 0; d < ND; ++d) {
            out[((((size_t)(b * 2 * ND + d)) * NP + n) << 4) + k0 + t] = xv[d];
        }
    }
    const float* fb = features + (size_t)b * ND * NP;
#pragma unroll
    for (int d = 0; d < ND; ++d) {
        const float v = fb[d * NP + n];
        *(float4*)(out + ((((size_t)(b * 2 * ND + ND + d)) * NP + n) << 4) + k0) =
            make_float4(v, v, v, v);
    }
}

extern "C" void kernel_launch(void* const* d_in, const int* in_sizes, int n_in,
                              void* d_out, int out_size, void* d_ws, size_t ws_size,
                              hipStream_t stream) {
    const float* coords   = (const float*)d_in[0];
    const float* features = (const float*)d_in[1];
    const int*   knn_idx  = (const int*)  d_in[2];
    const float* knn_dist = (const float*)d_in[3];
    const int*   mask     = (const int*)  d_in[4];
    const float* conv_w   = (const float*)d_in[5];
    const float* conv_b   = (const float*)d_in[6];
    const float* bn_gamma = (const float*)d_in[7];
    const float* bn_beta  = (const float*)d_in[8];
    float* out   = (float*)d_out;
    float* accum = (float*)d_ws;   // 4 banks x 16 floats

    hipMemsetAsync(d_ws, 0, 256, stream);

    void* args[] = {
        (void*)&coords, (void*)&features, (void*)&knn_idx, (void*)&knn_dist,
        (void*)&mask, (void*)&conv_w, (void*)&conv_b, (void*)&bn_gamma,
        (void*)&bn_beta, (void*)&accum, (void*)&out,
    };
    hipError_t e = hipLaunchCooperativeKernel(
        (const void*)lse_fused, dim3(2048), dim3(256), args, 0, stream);

    if (e != hipSuccess) {
        (void)hipGetLastError();   // clear sticky error, use two-pass fallback
        lse_stats<<<2048, 256, 0, stream>>>(
            coords, knn_idx, knn_dist, mask, conv_w, conv_b, accum);
        lse_write<<<2048, 256, 0, stream>>>(
            coords, features, knn_idx, knn_dist, mask, conv_w, conv_b,
            accum, bn_gamma, bn_beta, out);
    }
}

// Round 3
// 200.845 us; speedup vs baseline: 2.5662x; 2.5662x over previous
//
#include <hip/hip_runtime.h>
#include <hip/hip_fp16.h>

#define NB 4
#define NP 32768
#define NK 16
#define ND 8
#define EPSV 1e-6f

// d_ws layout: [0..256)  : 4 banks x 16 float accumulators (sum[8], sumsq[8] per bank)
//              [256..)   : fp16 x-stage, (B,D,N,K) = 32 MB
// Structure: round-0 two-pass fp16-stage design (best measured: 194.6 us) +
//   - 4-way banked stats atomics (cuts same-address serialization 4x)
//   - nontemporal stores for ALL final output (write-once; keeps stage+inputs
//     L2/L3-resident instead of being thrashed by 134 MB of streaming writes)

__device__ __forceinline__ void nt_store_f4(float* p, float4 v) {
    __builtin_nontemporal_store(v.x, p + 0);
    __builtin_nontemporal_store(v.y, p + 1);
    __builtin_nontemporal_store(v.z, p + 2);
    __builtin_nontemporal_store(v.w, p + 3);
}

// ---------------- Pass 1: gather + conv, stage x fp16, feature planes, stats ----------
// one thread per (b, n, kq) with kq = k/4  ->  4*32768*4 = 524288 threads, 2048 blocks
__global__ __launch_bounds__(256) void lse_pass1(
    const float* __restrict__ coords,
    const float* __restrict__ features,
    const int*   __restrict__ knn_idx,
    const float* __restrict__ knn_dist,
    const int*   __restrict__ mask,
    const float* __restrict__ conv_w,
    const float* __restrict__ conv_b,
    float*       __restrict__ accum,
    __half*      __restrict__ xstage,   // nullptr -> stage fp32 into out instead
    float*       __restrict__ out)
{
    const int gid = blockIdx.x * 256 + threadIdx.x;
    const int b   = gid >> 17;                 // NP*4 = 2^17 threads per batch
    const int r   = gid & (NP * 4 - 1);
    const int n   = r >> 2;
    const int k0  = (r & 3) * 4;

    // Folded 1x1-conv weights: x_d = a.c + e.c_j + w9*dist + cb   (thread-uniform)
    float a0[ND], a1[ND], a2[ND], e0[ND], e1[ND], e2[ND], w9[ND], cb[ND];
#pragma unroll
    for (int d = 0; d < ND; ++d) {
        const float* w = conv_w + d * 10;
        a0[d] = w[0] + w[6]; a1[d] = w[1] + w[7]; a2[d] = w[2] + w[8];
        e0[d] = w[3] - w[6]; e1[d] = w[4] - w[7]; e2[d] = w[5] - w[8];
        w9[d] = w[9];        cb[d] = conv_b[d];
    }

    const float* cbase = coords + (size_t)b * NP * 3;
    const float  cx = cbase[n * 3 + 0];
    const float  cy = cbase[n * 3 + 1];
    const float  cz = cbase[n * 3 + 2];

    const size_t p  = ((size_t)(b * NP + n)) * NK + k0;
    const int4   id = *(const int4*)(knn_idx + p);     // 16B coalesced
    float4       dv = *(const float4*)(knn_dist + p);  // 16B coalesced
    if (mask[b * NP + n] == 0) {
        dv.x = dv.y = dv.z = dv.w = __builtin_inff();
    }

    const int   js[4] = {id.x < 0 ? 0 : id.x, id.y < 0 ? 0 : id.y,
                         id.z < 0 ? 0 : id.z, id.w < 0 ? 0 : id.w};
    const float ds[4] = {dv.x, dv.y, dv.z, dv.w};

    float xv[4][ND];
    float sum[ND], sq[ND];
#pragma unroll
    for (int d = 0; d < ND; ++d) { sum[d] = 0.f; sq[d] = 0.f; }

#pragma unroll
    for (int t = 0; t < 4; ++t) {
        const float* nb = cbase + (size_t)js[t] * 3;   // L1/L2-resident gather
        const float  nx = nb[0], ny = nb[1], nz = nb[2];
#pragma unroll
        for (int d = 0; d < ND; ++d) {
            float x = fmaf(a0[d], cx, fmaf(a1[d], cy, fmaf(a2[d], cz,
                      fmaf(e0[d], nx, fmaf(e1[d], ny, fmaf(e2[d], nz,
                      fmaf(w9[d], ds[t], cb[d])))))));
            xv[t][d] = x;
            sum[d] += x;
            sq[d]   = fmaf(x, x, sq[d]);
        }
    }

    // stage x: fp16 into ws (normal stores -> stays L2/L3-resident for pass 2)
    if (xstage) {
#pragma unroll
        for (int d = 0; d < ND; ++d) {
            __half2* o2 = (__half2*)(xstage +
                ((((size_t)(b * ND + d)) * NP + n) << 4) + k0);   // 8B aligned
            o2[0] = __floats2half2_rn(xv[0][d], xv[1][d]);
            o2[1] = __floats2half2_rn(xv[2][d], xv[3][d]);
        }
    } else {
#pragma unroll
        for (int d = 0; d < ND; ++d) {
            *(float4*)(out + ((((size_t)(b * 2 * ND + d)) * NP + n) << 4) + k0) =
                make_float4(xv[0][d], xv[1][d], xv[2][d], xv[3][d]);
        }
    }

    // BN-independent feature broadcast planes (channels ND..2ND-1): write-once ->
    // nontemporal, don't pollute caches needed by the stage + gathers.
    const float* fb = features + (size_t)b * ND * NP;
#pragma unroll
    for (int d = 0; d < ND; ++d) {
        const float v = fb[d * NP + n];
        nt_store_f4(out + ((((size_t)(b * 2 * ND + ND + d)) * NP + n) << 4) + k0,
                    make_float4(v, v, v, v));
    }

    // ---- stats reduction: wave shuffle -> LDS -> 16 atomics into bank (blk&3) ----
#pragma unroll
    for (int d = 0; d < ND; ++d) {
        float s = sum[d], s2 = sq[d];
#pragma unroll
        for (int off = 32; off > 0; off >>= 1) {
            s  += __shfl_down(s,  off);
            s2 += __shfl_down(s2, off);
        }
        sum[d] = s; sq[d] = s2;
    }
    __shared__ float lred[4][16];
    const int wave = threadIdx.x >> 6, lane = threadIdx.x & 63;
    if (lane == 0) {
#pragma unroll
        for (int d = 0; d < ND; ++d) {
            lred[wave][d]     = sum[d];
            lred[wave][8 + d] = sq[d];
        }
    }
    __syncthreads();
    if (threadIdx.x < 16) {
        float v = lred[0][threadIdx.x] + lred[1][threadIdx.x]
                + lred[2][threadIdx.x] + lred[3][threadIdx.x];
        atomicAdd(&accum[(blockIdx.x & 3) * 16 + threadIdx.x], v);
    }
}

// ---------------- Pass 2: normalize + relu, streaming ----------------------------------
// one thread per 8 x-elements -> 16777216/8 = 2097152 threads, 8192 blocks
__global__ __launch_bounds__(256) void lse_pass2(
    const float*  __restrict__ accum,
    const float*  __restrict__ bn_gamma,
    const float*  __restrict__ bn_beta,
    const __half* __restrict__ xstage,   // nullptr -> x staged fp32 in out
    float*        __restrict__ out)
{
    const int    gid = blockIdx.x * 256 + threadIdx.x;
    const size_t s0  = (size_t)gid * 8;              // flat (b,d,n,k) x-index
    const int    d   = (int)((s0 >> 19) & 7);        // plane = NP*NK = 2^19
    const int    b   = (int)(s0 >> 22);              // 8 planes per batch
    const size_t inp = s0 & ((1u << 19) - 1);
    const size_t o   = (((size_t)(b * 2 * ND + d)) << 19) | inp;

    // combine 4 accumulator banks (L1-hit loads, uniform per wave in practice)
    const float fsum = accum[d]      + accum[16 + d]
                     + accum[32 + d] + accum[48 + d];
    const float fsq  = accum[8 + d]  + accum[24 + d]
                     + accum[40 + d] + accum[56 + d];

    const float invM = 1.0f / (float)(NB * NP * NK);
    const float mean = fsum * invM;
    const float var  = fmaf(-mean, mean, fsq * invM);
    const float g    = bn_gamma[d] * rsqrtf(var + EPSV);
    const float sh   = fmaf(-mean, g, bn_beta[d]);

    float x[8];
    if (xstage) {
        const float4 raw = *(const float4*)(xstage + s0);   // 8 halfs, 16B (L3-hit)
        const __half2* h = (const __half2*)&raw;
#pragma unroll
        for (int q = 0; q < 4; ++q) {
            float2 f = __half22float2(h[q]);
            x[2 * q]     = f.x;
            x[2 * q + 1] = f.y;
        }
    } else {
        const float4 v0 = *(const float4*)(out + o);
        const float4 v1 = *(const float4*)(out + o + 4);
        x[0] = v0.x; x[1] = v0.y; x[2] = v0.z; x[3] = v0.w;
        x[4] = v1.x; x[5] = v1.y; x[6] = v1.z; x[7] = v1.w;
    }

    float4 r0, r1;
    r0.x = fmaxf(fmaf(x[0], g, sh), 0.f);
    r0.y = fmaxf(fmaf(x[1], g, sh), 0.f);
    r0.z = fmaxf(fmaf(x[2], g, sh), 0.f);
    r0.w = fmaxf(fmaf(x[3], g, sh), 0.f);
    r1.x = fmaxf(fmaf(x[4], g, sh), 0.f);
    r1.y = fmaxf(fmaf(x[5], g, sh), 0.f);
    r1.z = fmaxf(fmaf(x[6], g, sh), 0.f);
    r1.w = fmaxf(fmaf(x[7], g, sh), 0.f);
    nt_store_f4(out + o,     r0);
    nt_store_f4(out + o + 4, r1);
}

extern "C" void kernel_launch(void* const* d_in, const int* in_sizes, int n_in,
                              void* d_out, int out_size, void* d_ws, size_t ws_size,
                              hipStream_t stream) {
    const float* coords   = (const float*)d_in[0];
    const float* features = (const float*)d_in[1];
    const int*   knn_idx  = (const int*)  d_in[2];
    const float* knn_dist = (const float*)d_in[3];
    const int*   mask     = (const int*)  d_in[4];
    const float* conv_w   = (const float*)d_in[5];
    const float* conv_b   = (const float*)d_in[6];
    const float* bn_gamma = (const float*)d_in[7];
    const float* bn_beta  = (const float*)d_in[8];
    float* out   = (float*)d_out;
    float* accum = (float*)d_ws;   // 4 banks x 16 floats

    hipMemsetAsync(d_ws, 0, 256, stream);

    __half* xstage = nullptr;
    const size_t need = 256 + (size_t)NB * ND * NP * NK * sizeof(__half);  // ~32 MB
    if (ws_size >= need) xstage = (__half*)((char*)d_ws + 256);

    // pass 1: 524288 threads
    lse_pass1<<<(NB * NP * 4) / 256, 256, 0, stream>>>(
        coords, features, knn_idx, knn_dist, mask, conv_w, conv_b,
        accum, xstage, out);

    // pass 2: 2097152 threads
    lse_pass2<<<(NB * ND * NP * NK / 8) / 256, 256, 0, stream>>>(
        accum, bn_gamma, bn_beta, xstage, out);
}

// Round 4
// 195.755 us; speedup vs baseline: 2.6329x; 1.0260x over previous
//
#include <hip/hip_runtime.h>
#include <hip/hip_fp16.h>

#define NB 4
#define NP 32768
#define NK 16
#define ND 8
#define EPSV 1e-6f

// d_ws layout: [0..256)  : 4 banks x 16 float accumulators (sum[8], sumsq[8] per bank)
//              [256..)   : fp16 x-stage, (B,D,N,K) = 32 MB
// Proven round-0 structure (194.6 us measured) + 4-way banked stats atomics.
// NT stores removed: scalar-split nontemporal stores cost ~6 us (round-3 post-mortem).

// ---------------- Pass 1: gather + conv, stage x fp16, feature planes, stats ----------
// one thread per (b, n, kq) with kq = k/4  ->  4*32768*4 = 524288 threads, 2048 blocks
__global__ __launch_bounds__(256) void lse_pass1(
    const float* __restrict__ coords,
    const float* __restrict__ features,
    const int*   __restrict__ knn_idx,
    const float* __restrict__ knn_dist,
    const int*   __restrict__ mask,
    const float* __restrict__ conv_w,
    const float* __restrict__ conv_b,
    float*       __restrict__ accum,
    __half*      __restrict__ xstage,   // nullptr -> stage fp32 into out instead
    float*       __restrict__ out)
{
    const int gid = blockIdx.x * 256 + threadIdx.x;
    const int b   = gid >> 17;                 // NP*4 = 2^17 threads per batch
    const int r   = gid & (NP * 4 - 1);
    const int n   = r >> 2;
    const int k0  = (r & 3) * 4;

    // Folded 1x1-conv weights: x_d = a.c + e.c_j + w9*dist + cb   (thread-uniform)
    float a0[ND], a1[ND], a2[ND], e0[ND], e1[ND], e2[ND], w9[ND], cb[ND];
#pragma unroll
    for (int d = 0; d < ND; ++d) {
        const float* w = conv_w + d * 10;
        a0[d] = w[0] + w[6]; a1[d] = w[1] + w[7]; a2[d] = w[2] + w[8];
        e0[d] = w[3] - w[6]; e1[d] = w[4] - w[7]; e2[d] = w[5] - w[8];
        w9[d] = w[9];        cb[d] = conv_b[d];
    }

    const float* cbase = coords + (size_t)b * NP * 3;
    const float  cx = cbase[n * 3 + 0];
    const float  cy = cbase[n * 3 + 1];
    const float  cz = cbase[n * 3 + 2];

    const size_t p  = ((size_t)(b * NP + n)) * NK + k0;
    const int4   id = *(const int4*)(knn_idx + p);     // 16B coalesced
    float4       dv = *(const float4*)(knn_dist + p);  // 16B coalesced
    if (mask[b * NP + n] == 0) {
        dv.x = dv.y = dv.z = dv.w = __builtin_inff();
    }

    const int   js[4] = {id.x < 0 ? 0 : id.x, id.y < 0 ? 0 : id.y,
                         id.z < 0 ? 0 : id.z, id.w < 0 ? 0 : id.w};
    const float ds[4] = {dv.x, dv.y, dv.z, dv.w};

    float xv[4][ND];
    float sum[ND], sq[ND];
#pragma unroll
    for (int d = 0; d < ND; ++d) { sum[d] = 0.f; sq[d] = 0.f; }

#pragma unroll
    for (int t = 0; t < 4; ++t) {
        const float* nb = cbase + (size_t)js[t] * 3;   // L1/L2-resident gather
        const float  nx = nb[0], ny = nb[1], nz = nb[2];
#pragma unroll
        for (int d = 0; d < ND; ++d) {
            float x = fmaf(a0[d], cx, fmaf(a1[d], cy, fmaf(a2[d], cz,
                      fmaf(e0[d], nx, fmaf(e1[d], ny, fmaf(e2[d], nz,
                      fmaf(w9[d], ds[t], cb[d])))))));
            xv[t][d] = x;
            sum[d] += x;
            sq[d]   = fmaf(x, x, sq[d]);
        }
    }

    // stage x: fp16 into ws (preferred) or fp32 into out
    if (xstage) {
#pragma unroll
        for (int d = 0; d < ND; ++d) {
            __half2* o2 = (__half2*)(xstage +
                ((((size_t)(b * ND + d)) * NP + n) << 4) + k0);   // 8B aligned
            o2[0] = __floats2half2_rn(xv[0][d], xv[1][d]);
            o2[1] = __floats2half2_rn(xv[2][d], xv[3][d]);
        }
    } else {
#pragma unroll
        for (int d = 0; d < ND; ++d) {
            *(float4*)(out + ((((size_t)(b * 2 * ND + d)) * NP + n) << 4) + k0) =
                make_float4(xv[0][d], xv[1][d], xv[2][d], xv[3][d]);
        }
    }

    // BN-independent feature broadcast planes (channels ND..2ND-1)
    const float* fb = features + (size_t)b * ND * NP;
#pragma unroll
    for (int d = 0; d < ND; ++d) {
        const float v = fb[d * NP + n];
        *(float4*)(out + ((((size_t)(b * 2 * ND + ND + d)) * NP + n) << 4) + k0) =
            make_float4(v, v, v, v);
    }

    // ---- stats reduction: wave shuffle -> LDS -> 16 atomics into bank (blk&3) ----
#pragma unroll
    for (int d = 0; d < ND; ++d) {
        float s = sum[d], s2 = sq[d];
#pragma unroll
        for (int off = 32; off > 0; off >>= 1) {
            s  += __shfl_down(s,  off);
            s2 += __shfl_down(s2, off);
        }
        sum[d] = s; sq[d] = s2;
    }
    __shared__ float lred[4][16];
    const int wave = threadIdx.x >> 6, lane = threadIdx.x & 63;
    if (lane == 0) {
#pragma unroll
        for (int d = 0; d < ND; ++d) {
            lred[wave][d]     = sum[d];
            lred[wave][8 + d] = sq[d];
        }
    }
    __syncthreads();
    if (threadIdx.x < 16) {
        float v = lred[0][threadIdx.x] + lred[1][threadIdx.x]
                + lred[2][threadIdx.x] + lred[3][threadIdx.x];
        atomicAdd(&accum[(blockIdx.x & 3) * 16 + threadIdx.x], v);
    }
}

// ---------------- Pass 2: normalize + relu, streaming ----------------------------------
// one thread per 8 x-elements -> 16777216/8 = 2097152 threads, 8192 blocks
__global__ __launch_bounds__(256) void lse_pass2(
    const float*  __restrict__ accum,
    const float*  __restrict__ bn_gamma,
    const float*  __restrict__ bn_beta,
    const __half* __restrict__ xstage,   // nullptr -> x staged fp32 in out
    float*        __restrict__ out)
{
    const int    gid = blockIdx.x * 256 + threadIdx.x;
    const size_t s0  = (size_t)gid * 8;              // flat (b,d,n,k) x-index
    const int    d   = (int)((s0 >> 19) & 7);        // plane = NP*NK = 2^19
    const int    b   = (int)(s0 >> 22);              // 8 planes per batch
    const size_t inp = s0 & ((1u << 19) - 1);
    const size_t o   = (((size_t)(b * 2 * ND + d)) << 19) | inp;

    // combine 4 accumulator banks (uniform, L1-hit)
    const float fsum = accum[d]      + accum[16 + d]
                     + accum[32 + d] + accum[48 + d];
    const float fsq  = accum[8 + d]  + accum[24 + d]
                     + accum[40 + d] + accum[56 + d];

    const float invM = 1.0f / (float)(NB * NP * NK);
    const float mean = fsum * invM;
    const float var  = fmaf(-mean, mean, fsq * invM);
    const float g    = bn_gamma[d] * rsqrtf(var + EPSV);
    const float sh   = fmaf(-mean, g, bn_beta[d]);

    float x[8];
    if (xstage) {
        const float4 raw = *(const float4*)(xstage + s0);   // 8 halfs, 16B
        const __half2* h = (const __half2*)&raw;
#pragma unroll
        for (int q = 0; q < 4; ++q) {
            float2 f = __half22float2(h[q]);
            x[2 * q]     = f.x;
            x[2 * q + 1] = f.y;
        }
    } else {
        const float4 v0 = *(const float4*)(out + o);
        const float4 v1 = *(const float4*)(out + o + 4);
        x[0] = v0.x; x[1] = v0.y; x[2] = v0.z; x[3] = v0.w;
        x[4] = v1.x; x[5] = v1.y; x[6] = v1.z; x[7] = v1.w;
    }

    float4 r0, r1;
    r0.x = fmaxf(fmaf(x[0], g, sh), 0.f);
    r0.y = fmaxf(fmaf(x[1], g, sh), 0.f);
    r0.z = fmaxf(fmaf(x[2], g, sh), 0.f);
    r0.w = fmaxf(fmaf(x[3], g, sh), 0.f);
    r1.x = fmaxf(fmaf(x[4], g, sh), 0.f);
    r1.y = fmaxf(fmaf(x[5], g, sh), 0.f);
    r1.z = fmaxf(fmaf(x[6], g, sh), 0.f);
    r1.w = fmaxf(fmaf(x[7], g, sh), 0.f);
    *(float4*)(out + o)     = r0;
    *(float4*)(out + o + 4) = r1;
}

extern "C" void kernel_launch(void* const* d_in, const int* in_sizes, int n_in,
                              void* d_out, int out_size, void* d_ws, size_t ws_size,
                              hipStream_t stream) {
    const float* coords   = (const float*)d_in[0];
    const float* features = (const float*)d_in[1];
    const int*   knn_idx  = (const int*)  d_in[2];
    const float* knn_dist = (const float*)d_in[3];
    const int*   mask     = (const int*)  d_in[4];
    const float* conv_w   = (const float*)d_in[5];
    const float* conv_b   = (const float*)d_in[6];
    const float* bn_gamma = (const float*)d_in[7];
    const float* bn_beta  = (const float*)d_in[8];
    float* out   = (float*)d_out;
    float* accum = (float*)d_ws;   // 4 banks x 16 floats

    hipMemsetAsync(d_ws, 0, 256, stream);

    __half* xstage = nullptr;
    const size_t need = 256 + (size_t)NB * ND * NP * NK * sizeof(__half);  // ~32 MB
    if (ws_size >= need) xstage = (__half*)((char*)d_ws + 256);

    // pass 1: 524288 threads
    lse_pass1<<<(NB * NP * 4) / 256, 256, 0, stream>>>(
        coords, features, knn_idx, knn_dist, mask, conv_w, conv_b,
        accum, xstage, out);

    // pass 2: 2097152 threads
    lse_pass2<<<(NB * ND * NP * NK / 8) / 256, 256, 0, stream>>>(
        accum, bn_gamma, bn_beta, xstage, out);
}